// Round 7
// baseline (354.264 us; speedup 1.0000x reference)
//
#include <hip/hip_runtime.h>
#include <hip/hip_cooperative_groups.h>

namespace cg = cooperative_groups;

#define NN 4096
#define HH 64
#define TT 6
#define GG 16
#define NBLK 256

typedef __bf16 bf16x8 __attribute__((ext_vector_type(8)));
typedef float f32x4 __attribute__((ext_vector_type(4)));
typedef _Float16 h4 __attribute__((ext_vector_type(4)));

// ws layout (float offsets) — round-3 proven layout
constexpr int OFF_OFFS = 0;                         // ints [0..16]
constexpr int OFF_QS   = 32;                        // silu(q)*scale_q : N*64
constexpr int OFF_KS   = OFF_QS + NN * HH;          // silu(k)
constexpr int OFF_VS   = OFF_KS + NN * HH;          // v
constexpr int OFF_COS  = OFF_VS + NN * HH;          // cos(phase) N*8
constexpr int OFF_SIN  = OFF_COS + NN * 8;
constexpr int OFF_KVG  = OFF_SIN + NN * 8;          // kv_graph G*T*64*64 f32
constexpr int OFF_UPD  = OFF_KVG + GG * TT * HH * HH; // update f32 [N][64]

struct P1Sm { _Float16 WroH[64 * 66]; _Float16 WqH[192 * 66]; };          // 33.8 KB
struct P2Sm { float kr[8][64]; float v[8][64]; };                          // 4 KB
struct P4Sm { float sr[64][65]; float up[64][68]; float w[64][68]; };      // 50.2 KB
union SMemU { P1Sm p1; P2Sm p2; P4Sm p4; };                                // < 64 KB

__device__ __forceinline__ bf16x8 make_afrag(const float* p, float s) {
    float4 u0 = *(const float4*)p;
    float4 u1 = *(const float4*)(p + 4);
    bf16x8 r;
    r[0] = (__bf16)(s * u0.x); r[1] = (__bf16)(s * u0.y); r[2] = (__bf16)(s * u0.z); r[3] = (__bf16)(s * u0.w);
    r[4] = (__bf16)(s * u1.x); r[5] = (__bf16)(s * u1.y); r[6] = (__bf16)(s * u1.z); r[7] = (__bf16)(s * u1.w);
    return r;
}
__device__ __forceinline__ bf16x8 make_bfrag(const float* p) {
    float4 u0 = *(const float4*)p;
    float4 u1 = *(const float4*)(p + 4);
    bf16x8 r;
    r[0] = (__bf16)u0.x; r[1] = (__bf16)u0.y; r[2] = (__bf16)u0.z; r[3] = (__bf16)u0.w;
    r[4] = (__bf16)u1.x; r[5] = (__bf16)u1.y; r[6] = (__bf16)u1.z; r[7] = (__bf16)u1.w;
    return r;
}

// ================= P1: offsets + zeroing + QKV/silu/trig (round-2 proven body, fp16 weights) =================
__device__ __forceinline__ void p1_body(P1Sm& sm, int tid, int blk,
                                        const float* __restrict__ feat,
                                        const float* __restrict__ pos,
                                        const float* __restrict__ kvecs,
                                        const int* __restrict__ batch,
                                        const float* __restrict__ Wro,
                                        const float* __restrict__ Wqkv,
                                        float* __restrict__ ws,
                                        float* __restrict__ out) {
    if (blk == 0 && tid <= GG) {            // segment offsets via binary search
        int g = tid, lo = 0, hi = NN;
        while (lo < hi) { int mid = (lo + hi) >> 1; if (batch[mid] < g) lo = mid + 1; else hi = mid; }
        ((int*)(ws + OFF_OFFS))[g] = lo;
    }
    {   // zero kvg slice (384 float4/block) and out slice (256 float4/block)
        float4 z = {0.f, 0.f, 0.f, 0.f};
        float4* kz = (float4*)(ws + OFF_KVG) + blk * 384;
        kz[tid] = z;
        if (tid < 128) kz[256 + tid] = z;
        ((float4*)out)[blk * 256 + tid] = z;
    }
    #pragma unroll
    for (int k = 0; k < 8; ++k) {           // Wro: 2048 float2 -> fp16 LDS [r][66]
        int e2 = k * 256 + tid;
        float2 v = ((const float2*)Wro)[e2];
        int r = e2 >> 5, c2 = e2 & 31;
        _Float16* dst = &sm.WroH[r * 66 + c2 * 2];
        dst[0] = (_Float16)v.x; dst[1] = (_Float16)v.y;
    }
    #pragma unroll
    for (int k = 0; k < 24; ++k) {          // Wqkv: 6144 float2 -> fp16 LDS [r][66]
        int e2 = k * 256 + tid;
        float2 v = ((const float2*)Wqkv)[e2];
        int r = e2 >> 5, c2 = e2 & 31;
        _Float16* dst = &sm.WqH[r * 66 + c2 * 2];
        dst[0] = (_Float16)v.x; dst[1] = (_Float16)v.y;
    }
    __syncthreads();
    int w = tid >> 6, j = tid & 63;
    float fl[4];
    #pragma unroll
    for (int mi = 0; mi < 4; ++mi) fl[mi] = feat[(blk * 16 + w * 4 + mi) * 64 + j];
    float scal[4] = {0.f, 0.f, 0.f, 0.f};
    #pragma unroll
    for (int i4 = 0; i4 < 16; ++i4) {
        h4 w4 = *(const h4*)&sm.WroH[j * 66 + i4 * 4];
        float w0 = (float)w4[0], w1 = (float)w4[1], w2 = (float)w4[2], w3 = (float)w4[3];
        #pragma unroll
        for (int mi = 0; mi < 4; ++mi) {
            scal[mi] += __shfl(fl[mi], i4 * 4 + 0, 64) * w0
                      + __shfl(fl[mi], i4 * 4 + 1, 64) * w1
                      + __shfl(fl[mi], i4 * 4 + 2, 64) * w2
                      + __shfl(fl[mi], i4 * 4 + 3, 64) * w3;
        }
    }
    float qa[4] = {0.f,0.f,0.f,0.f}, ka[4] = {0.f,0.f,0.f,0.f}, va[4] = {0.f,0.f,0.f,0.f};
    #pragma unroll
    for (int i4 = 0; i4 < 16; ++i4) {
        h4 hq = *(const h4*)&sm.WqH[j * 66 + i4 * 4];
        h4 hk = *(const h4*)&sm.WqH[(64 + j) * 66 + i4 * 4];
        h4 hv = *(const h4*)&sm.WqH[(128 + j) * 66 + i4 * 4];
        #pragma unroll
        for (int mi = 0; mi < 4; ++mi) {
            float s0 = __shfl(scal[mi], i4 * 4 + 0, 64);
            float s1 = __shfl(scal[mi], i4 * 4 + 1, 64);
            float s2 = __shfl(scal[mi], i4 * 4 + 2, 64);
            float s3 = __shfl(scal[mi], i4 * 4 + 3, 64);
            qa[mi] += s0 * (float)hq[0] + s1 * (float)hq[1] + s2 * (float)hq[2] + s3 * (float)hq[3];
            ka[mi] += s0 * (float)hk[0] + s1 * (float)hk[1] + s2 * (float)hk[2] + s3 * (float)hk[3];
            va[mi] += s0 * (float)hv[0] + s1 * (float)hv[1] + s2 * (float)hv[2] + s3 * (float)hv[3];
        }
    }
    #pragma unroll
    for (int mi = 0; mi < 4; ++mi) {
        int n = blk * 16 + w * 4 + mi;
        float q = qa[mi], kk2 = ka[mi], v = va[mi];
        float qs = q / (1.f + __expf(-q)) * 0.125f;   // silu * scale_q (rope is linear)
        float ks = kk2 / (1.f + __expf(-kk2));
        ws[OFF_QS + n * 64 + j] = qs;
        ws[OFF_KS + n * 64 + j] = ks;
        ws[OFF_VS + n * 64 + j] = v;
        if (j < 6) {
            int g = batch[n];
            const float* kv = &kvecs[(g * 6 + j) * 3];
            float ph = pos[n * 3 + 0] * kv[0] + pos[n * 3 + 1] * kv[1] + pos[n * 3 + 2] * kv[2];
            ws[OFF_COS + n * 8 + j] = cosf(ph);
            ws[OFF_SIN + n * 8 + j] = sinf(ph);
        }
    }
}

// ================= P2: kv_graph segment-sum (round-3 proven body, unit = 0..767) =================
__device__ __forceinline__ void p2_body(P2Sm& sm, int tid, int u, float* __restrict__ ws) {
    const int* off = (const int*)(ws + OFF_OFFS);
    int g = u / 48, rem = u % 48, t = rem >> 3, ch = rem & 7;
    int n0 = off[g] + ch * 64;
    int n1 = min(off[g + 1], n0 + 64);
    if (n0 >= n1) return;                  // uniform over block
    int e = tid & 63, dg = tid >> 6;
    float acc[16];
    #pragma unroll
    for (int k = 0; k < 16; ++k) acc[k] = 0.f;
    for (int base = n0; base < n1; base += 8) {
        int cnt = min(8, n1 - base);
        #pragma unroll
        for (int half = 0; half < 2; ++half) {
            int idx = half * 256 + tid;
            int ns = idx >> 6, d = idx & 63;
            float kr = 0.f, vv = 0.f;
            if (ns < cnt) {
                int n = base + ns;
                float ka2 = ws[OFF_KS + n * 64 + 2 * (d & 31)];
                float kb = ws[OFF_KS + n * 64 + 2 * (d & 31) + 1];
                float c = ws[OFF_COS + n * 8 + t], s = ws[OFF_SIN + n * 8 + t];
                kr = (d < 32) ? (ka2 * c - kb * s) : (ka2 * s + kb * c);
                vv = ws[OFF_VS + n * 64 + d];
            }
            sm.kr[ns][d] = kr; sm.v[ns][d] = vv;
        }
        __syncthreads();
        #pragma unroll
        for (int ns = 0; ns < 8; ++ns) {
            float vv = sm.v[ns][e];
            const float4* kp = (const float4*)&sm.kr[ns][dg * 16];
            #pragma unroll
            for (int q4 = 0; q4 < 4; ++q4) {
                float4 kq = kp[q4];
                acc[q4 * 4 + 0] += kq.x * vv; acc[q4 * 4 + 1] += kq.y * vv;
                acc[q4 * 4 + 2] += kq.z * vv; acc[q4 * 4 + 3] += kq.w * vv;
            }
        }
        __syncthreads();
    }
    float* kvg = ws + OFF_KVG + ((g * 6 + t) * 64 + dg * 16) * 64;
    #pragma unroll
    for (int k = 0; k < 16; ++k) atomicAdd(&kvg[k * 64 + e], acc[k]);
}

// ================= P3: update via bf16 MFMA (round-3 proven body, unit = 0..511) =================
__device__ __forceinline__ void p3_body(int tid, int u, float* __restrict__ ws) {
    const int* off = (const int*)(ws + OFF_OFFS);
    int g = u >> 5, ch = u & 31;
    int n0 = off[g] + ch * 16;
    int nend = off[g + 1];
    if (n0 >= nend) return;
    int w = tid >> 6, lane = tid & 63, lr = lane & 15, lg = lane >> 4;
    int nc = min(n0 + lr, nend - 1);
    float qv[16];
    const float* qsr = ws + OFF_QS + nc * 64 + lg * 16;
    #pragma unroll
    for (int u2 = 0; u2 < 4; ++u2) *(float4*)&qv[u2 * 4] = *(const float4*)&qsr[u2 * 4];
    float cs[8], sn[8];
    *(float4*)&cs[0] = *(const float4*)(ws + OFF_COS + nc * 8);
    *(float4*)&cs[4] = *(const float4*)(ws + OFF_COS + nc * 8 + 4);
    *(float4*)&sn[0] = *(const float4*)(ws + OFF_SIN + nc * 8);
    *(float4*)&sn[4] = *(const float4*)(ws + OFF_SIN + nc * 8 + 4);
    const float* kvg = ws + OFF_KVG + g * (TT * HH * HH);
    int col0 = w * 16 + lr;
    f32x4 acc0 = {0.f, 0.f, 0.f, 0.f};
    #pragma unroll
    for (int kk = 0; kk < 12; ++kk) {
        int t = kk >> 1;
        float c = cs[t], s = sn[t];
        bf16x8 afr;
        #pragma unroll
        for (int ii = 0; ii < 8; ++ii) {
            float a = qv[2 * ii], b = qv[2 * ii + 1];
            float rr = ((kk & 1) == 0) ? (a * c - b * s) : (a * s + b * c);
            afr[ii] = (__bf16)rr;
        }
        const float* bp = kvg + (kk * 32 + lg * 8) * 64;
        bf16x8 b0;
        #pragma unroll
        for (int i = 0; i < 8; ++i) b0[i] = (__bf16)bp[i * 64 + col0];
        acc0 = __builtin_amdgcn_mfma_f32_16x16x32_bf16(afr, b0, acc0, 0, 0, 0);
    }
    #pragma unroll
    for (int r = 0; r < 4; ++r) {
        int n = n0 + lg * 4 + r;
        if (n < nend) ws[OFF_UPD + n * 64 + col0] = acc0[r];
    }
}

// ================= P4: out GEMM (round-3 proven body, blk = 0..255 = 64 m-tiles x 4 ksplits) =================
__device__ __forceinline__ void p4_body(P4Sm& sm, int tid, int blk,
                                        const float* __restrict__ srf,
                                        const float* __restrict__ Wtp,
                                        float* __restrict__ ws,
                                        float* __restrict__ out) {
    int mb = blk & 63, kspl = blk >> 6;
    int m0 = mb * 64;
    #pragma unroll
    for (int k = 0; k < 16; ++k) {
        int idx = k * 256 + tid;      // 0..4095
        int m = idx >> 6, c = idx & 63;
        sm.sr[m][c] = srf[(m0 + m) * 64 + c];
        sm.up[m][c] = ws[OFF_UPD + (m0 + m) * 64 + c];
    }
    __syncthreads();
    int w = tid >> 6, lane = tid & 63;
    int wm = w >> 1, wn = w & 1;
    int lr = lane & 15, lg = lane >> 4;
    f32x4 acc[2][2];
    #pragma unroll
    for (int a = 0; a < 2; ++a)
        #pragma unroll
        for (int b = 0; b < 2; ++b) acc[a][b] = (f32x4){0.f, 0.f, 0.f, 0.f};

    for (int ii = 0; ii < 16; ++ii) {
        int i = kspl * 16 + ii;
        #pragma unroll
        for (int k = 0; k < 4; ++k) {
            int idx = k * 256 + tid;                    // 0..1023
            int col = idx >> 4, j4 = (idx & 15) * 4;
            float4 wv = *(const float4*)&Wtp[(col * 64 + i) * 64 + j4];
            *(float4*)&sm.w[col][j4] = wv;
        }
        __syncthreads();
        float s0 = sm.sr[wm * 32 + lr][i];
        float s1 = sm.sr[wm * 32 + 16 + lr][i];
        #pragma unroll
        for (int kc = 0; kc < 2; ++kc) {
            int j0 = kc * 32 + lg * 8;
            bf16x8 a0 = make_afrag(&sm.up[wm * 32 + lr][j0], s0);
            bf16x8 a1 = make_afrag(&sm.up[wm * 32 + 16 + lr][j0], s1);
            bf16x8 b0 = make_bfrag(&sm.w[wn * 32 + lr][j0]);
            bf16x8 b1 = make_bfrag(&sm.w[wn * 32 + 16 + lr][j0]);
            acc[0][0] = __builtin_amdgcn_mfma_f32_16x16x32_bf16(a0, b0, acc[0][0], 0, 0, 0);
            acc[0][1] = __builtin_amdgcn_mfma_f32_16x16x32_bf16(a0, b1, acc[0][1], 0, 0, 0);
            acc[1][0] = __builtin_amdgcn_mfma_f32_16x16x32_bf16(a1, b0, acc[1][0], 0, 0, 0);
            acc[1][1] = __builtin_amdgcn_mfma_f32_16x16x32_bf16(a1, b1, acc[1][1], 0, 0, 0);
        }
        __syncthreads();
    }
    #pragma unroll
    for (int mt = 0; mt < 2; ++mt)
        #pragma unroll
        for (int nt = 0; nt < 2; ++nt) {
            int row = m0 + wm * 32 + mt * 16 + lg * 4;
            int col = wn * 32 + nt * 16 + lr;
            #pragma unroll
            for (int r = 0; r < 4; ++r)
                atomicAdd(&out[(row + r) * 64 + col], acc[mt][nt][r]);
        }
}

__device__ __forceinline__ void gsync(cg::grid_group& g) {
    __threadfence();
    g.sync();
    __threadfence();
}

// ================= fused cooperative kernel =================
__global__ __launch_bounds__(256) void k_fused(const float* __restrict__ feat,
                                               const float* __restrict__ srf,
                                               const float* __restrict__ pos,
                                               const float* __restrict__ kvecs,
                                               const int* __restrict__ batch,
                                               const float* __restrict__ Wro,
                                               const float* __restrict__ Wqkv,
                                               const float* __restrict__ Wtp,
                                               float* __restrict__ ws,
                                               float* __restrict__ out) {
    __shared__ SMemU sm;
    cg::grid_group grid = cg::this_grid();
    int tid = threadIdx.x, blk = blockIdx.x;
    p1_body(sm.p1, tid, blk, feat, pos, kvecs, batch, Wro, Wqkv, ws, out);
    gsync(grid);
    for (int r = 0; r < 3; ++r) {
        p2_body(sm.p2, tid, blk * 3 + r, ws);
        __syncthreads();
    }
    gsync(grid);
    for (int r = 0; r < 2; ++r) p3_body(tid, blk * 2 + r, ws);
    gsync(grid);
    p4_body(sm.p4, tid, blk, srf, Wtp, ws, out);
}

// ================= fallback per-phase wrappers =================
__global__ __launch_bounds__(256) void k_p1(const float* __restrict__ feat,
                                            const float* __restrict__ pos,
                                            const float* __restrict__ kvecs,
                                            const int* __restrict__ batch,
                                            const float* __restrict__ Wro,
                                            const float* __restrict__ Wqkv,
                                            float* __restrict__ ws,
                                            float* __restrict__ out) {
    __shared__ P1Sm sm;
    p1_body(sm, threadIdx.x, blockIdx.x, feat, pos, kvecs, batch, Wro, Wqkv, ws, out);
}
__global__ __launch_bounds__(256) void k_p2(float* __restrict__ ws) {
    __shared__ P2Sm sm;
    p2_body(sm, threadIdx.x, blockIdx.x, ws);
}
__global__ __launch_bounds__(256) void k_p3(float* __restrict__ ws) {
    p3_body(threadIdx.x, blockIdx.x, ws);
}
__global__ __launch_bounds__(256) void k_p4(const float* __restrict__ srf,
                                            const float* __restrict__ Wtp,
                                            float* __restrict__ ws,
                                            float* __restrict__ out) {
    __shared__ P4Sm sm;
    p4_body(sm, threadIdx.x, blockIdx.x, srf, Wtp, ws, out);
}

extern "C" void kernel_launch(void* const* d_in, const int* in_sizes, int n_in,
                              void* d_out, int out_size, void* d_ws, size_t ws_size,
                              hipStream_t stream) {
    const float* node_feat    = (const float*)d_in[0];
    const float* node_feat_sr = (const float*)d_in[1];
    const float* positions    = (const float*)d_in[2];
    const float* kvecs        = (const float*)d_in[3];
    const int*   batch        = (const int*)d_in[4];
    const float* W_readout    = (const float*)d_in[5];
    const float* W_qkv        = (const float*)d_in[6];
    const float* W_tp         = (const float*)d_in[7];
    float* out = (float*)d_out;
    float* ws  = (float*)d_ws;

    void* args[] = {(void*)&node_feat, (void*)&node_feat_sr, (void*)&positions,
                    (void*)&kvecs, (void*)&batch, (void*)&W_readout, (void*)&W_qkv,
                    (void*)&W_tp, (void*)&ws, (void*)&out};
    hipError_t err = hipLaunchCooperativeKernel((const void*)k_fused, dim3(NBLK), dim3(256),
                                                args, 0, stream);
    if (err != hipSuccess) {
        // fallback: 4 separate dispatches (round-3-equivalent, proven)
        k_p1<<<NBLK, 256, 0, stream>>>(node_feat, positions, kvecs, batch,
                                       W_readout, W_qkv, ws, out);
        k_p2<<<768, 256, 0, stream>>>(ws);
        k_p3<<<512, 256, 0, stream>>>(ws);
        k_p4<<<NBLK, 256, 0, stream>>>(node_feat_sr, W_tp, ws, out);
    }
}